// Round 1
// baseline (114.469 us; speedup 1.0000x reference)
//
#include <hip/hip_runtime.h>
#include <hip/hip_bf16.h>

// Problem: B=2, L=64, F=128. Output (B, L, L, L, 2F) f32 = 134,217,728 elems.
// out[b,a,t,s,0:128]   = mask(a,t,s) * (P[b,max(a,s)]-P[b,min(a,s)])/max(|a-s|,1)
// out[b,a,t,s,128:256] = mask(a,t,s) * (P[b,max(t,s)]-P[b,min(t,s)])/max(|t-s|,1)
// where P = exclusive+inclusive cumsum of x along L (P[0]=0, P[k]=sum x[0..k-1]).
// Pure write-BW bound: 512 MiB out vs 64 KiB in.

#define B_ 2
#define L_ 64
#define F_ 128

// Prefix sums live in a small device-global buffer (66.5 KB) -> no ws_size
// assumptions. Recomputed fully on every call (deterministic).
__device__ float g_P[B_ * (L_ + 1) * F_];

__global__ void prefix_kernel(const float* __restrict__ x) {
    const int b = blockIdx.x;       // 0..1
    const int f = threadIdx.x;      // 0..127
    const float* xb = x + b * L_ * F_ + f;
    float* Pb = g_P + b * (L_ + 1) * F_ + f;

    // Load all 64 rows (independent loads, unrolled -> all in flight).
    float v[L_];
#pragma unroll
    for (int r = 0; r < L_; ++r) v[r] = xb[r * F_];

    float run = 0.0f;
    Pb[0] = 0.0f;
#pragma unroll
    for (int r = 0; r < L_; ++r) {
        run += v[r];
        Pb[(r + 1) * F_] = run;
    }
}

__global__ __launch_bounds__(256) void writer_kernel(float4* __restrict__ out,
                                                     int total4) {
    const int stride = gridDim.x * blockDim.x;
    for (int idx4 = blockIdx.x * blockDim.x + threadIdx.x; idx4 < total4;
         idx4 += stride) {
        // 64 float4 per (b,a,t,s); lane == f4 since stride is a multiple of 64.
        const int f4 = idx4 & 63;
        const int s  = (idx4 >> 6)  & 63;
        const int t  = (idx4 >> 12) & 63;
        const int a  = (idx4 >> 18) & 63;
        const int b  = idx4 >> 24;

        // Wave-uniform predicate: lanes of a wave share (b,a,t,s).
        const bool distinct = (a != t) & (a != s) & (t != s);

        float4 v;
        if (!distinct) {
            v = make_float4(0.f, 0.f, 0.f, 0.f);
        } else {
            // lanes 0..31: first half (i=a), lanes 32..63: second half (i=t)
            const int i  = (f4 < 32) ? a : t;
            const int fb = (f4 & 31) << 2;          // float offset within row
            const int lo = min(i, s);
            const int hi = max(i, s);
            const int d  = hi - lo;                  // >= 1 on this path
            const float* base = g_P + ((b * (L_ + 1)) << 7) + fb;
            const float4 phi = *reinterpret_cast<const float4*>(base + (hi << 7));
            const float4 plo = *reinterpret_cast<const float4*>(base + (lo << 7));
            const float r = __builtin_amdgcn_rcpf((float)d);  // exact for pow2, ~1ulp else
            v = make_float4((phi.x - plo.x) * r, (phi.y - plo.y) * r,
                            (phi.z - plo.z) * r, (phi.w - plo.w) * r);
        }
        out[idx4] = v;
    }
}

extern "C" void kernel_launch(void* const* d_in, const int* in_sizes, int n_in,
                              void* d_out, int out_size, void* d_ws, size_t ws_size,
                              hipStream_t stream) {
    const float* x = (const float*)d_in[0];
    float4* out = (float4*)d_out;
    const int total4 = out_size / 4;  // 33,554,432 float4 stores

    prefix_kernel<<<B_, F_, 0, stream>>>(x);
    writer_kernel<<<2048, 256, 0, stream>>>(out, total4);
}

// Round 3
// 109.620 us; speedup vs baseline: 1.0442x; 1.0442x over previous
//
#include <hip/hip_runtime.h>
#include <hip/hip_bf16.h>

// Problem: B=2, L=64, F=128. Output (B, L(a), L(t), L(s), 2F) f32 = 512 MiB.
// out[b,a,t,s,0:128]   = mask * (P[b,max(a,s)]-P[b,min(a,s)])/(|a-s|)
// out[b,a,t,s,128:256] = mask * (P[b,max(t,s)]-P[b,min(t,s)])/(|t-s|)
// mask = (a!=t)&(a!=s)&(t!=s).  Pure write-BW bound: 512 MiB out, 64 KiB in.

#define B_ 2
#define L_ 64
#define F_ 128

typedef float f32x4 __attribute__((ext_vector_type(4)));  // native vector for
                                                          // __builtin_nontemporal_store

__device__ float g_P[B_ * (L_ + 1) * F_];   // prefix sums, 66.5 KB

__global__ void prefix_kernel(const float* __restrict__ x) {
    const int b = blockIdx.x;       // 0..1
    const int f = threadIdx.x;      // 0..127
    const float* xb = x + b * L_ * F_ + f;
    float* Pb = g_P + b * (L_ + 1) * F_ + f;

    float v[L_];
#pragma unroll
    for (int r = 0; r < L_; ++r) v[r] = xb[r * F_];

    float run = 0.0f;
    Pb[0] = 0.0f;
#pragma unroll
    for (int r = 0; r < L_; ++r) {
        run += v[r];
        Pb[(r + 1) * F_] = run;
    }
}

// One block per (b,a,t). 256 threads = 4 waves; wave w owns s in [16w, 16w+16)
// -> each wave streams a contiguous 16 KiB. All per-block decode hoisted out
// of the store loop; loads of P are L1/L2-resident (66.5 KB total).
__global__ __launch_bounds__(256) void writer_kernel(f32x4* __restrict__ out) {
    const int bat = blockIdx.x;          // (b*64 + a)*64 + t
    const int t = bat & 63;
    const int a = (bat >> 6) & 63;
    const int b = bat >> 12;
    const int tid = threadIdx.x;
    const int f4 = tid & 63;             // float4 index within the 256-float row
    const int sw = tid >> 6;             // wave id 0..3
    const int s0 = sw << 4;              // this wave's first s
    f32x4* o = out + (size_t)bat * 4096 + s0 * 64 + f4;

    const f32x4 z = {0.f, 0.f, 0.f, 0.f};

    if (a == t) {                        // whole (a,t) plane is masked out
#pragma unroll
        for (int k = 0; k < 16; ++k)
            __builtin_nontemporal_store(z, o + k * 64);
        return;
    }

    // lanes 0..31 -> first half (i = a = lm); lanes 32..63 -> second (i = t = tr)
    const int i = (f4 < 32) ? a : t;
    const float* base = g_P + ((b * (L_ + 1)) << 7) + ((f4 & 31) << 2);

#pragma unroll
    for (int k = 0; k < 16; ++k) {
        const int s = s0 + k;            // wave-uniform
        f32x4 v;
        if (s == a || s == t) {          // wave-uniform branch
            v = z;
        } else {
            const int lo = min(i, s);
            const int hi = max(i, s);
            const float r = __builtin_amdgcn_rcpf((float)(hi - lo)); // d >= 1 here
            const f32x4 phi = *reinterpret_cast<const f32x4*>(base + (hi << 7));
            const f32x4 plo = *reinterpret_cast<const f32x4*>(base + (lo << 7));
            v = (phi - plo) * r;
        }
        __builtin_nontemporal_store(v, o + k * 64);
    }
}

extern "C" void kernel_launch(void* const* d_in, const int* in_sizes, int n_in,
                              void* d_out, int out_size, void* d_ws, size_t ws_size,
                              hipStream_t stream) {
    const float* x = (const float*)d_in[0];
    f32x4* out = (f32x4*)d_out;

    prefix_kernel<<<B_, F_, 0, stream>>>(x);
    writer_kernel<<<B_ * L_ * L_, 256, 0, stream>>>(out);
}